// Round 7
// baseline (81.227 us; speedup 1.0000x reference)
//
#include <hip/hip_runtime.h>
#include <stdint.h>

#define D_IN    2048
#define NT      15
#define PPT     14359      // 7*(2048+1) + 8*2
#define NVALID  60         // 15 trees * 4 used internal nodes

typedef __bf16   bf16x8 __attribute__((ext_vector_type(8)));
typedef float    f32x4  __attribute__((ext_vector_type(4)));
typedef uint32_t u32x4  __attribute__((ext_vector_type(4)));

#define WAITV(n) asm volatile("s_waitcnt vmcnt(" #n ")" ::: "memory")
#define WAITL0   asm volatile("s_waitcnt lgkmcnt(0)" ::: "memory")
#define SCHEDB   __builtin_amdgcn_sched_barrier(0)

// pack two floats -> (hi bf16 pair, lo bf16 pair); lo = residual of truncation
#define CVT_PAIR(P, Q, HW, LW) do {                                   \
    uint32_t _up = __float_as_uint(P), _uq = __float_as_uint(Q);      \
    uint32_t _mp = _up & 0xFFFF0000u, _mq = _uq & 0xFFFF0000u;        \
    (HW) = (_up >> 16) | _mq;                                         \
    float _lp = (P) - __uint_as_float(_mp);                           \
    float _lq = (Q) - __uint_as_float(_mq);                           \
    (LW) = (__float_as_uint(_lp) >> 16) |                             \
           (__float_as_uint(_lq) & 0xFFFF0000u);                      \
  } while (0)

__device__ __forceinline__ void cvt8(const f32x4 A, const f32x4 B,
                                     u32x4& hi, u32x4& lo) {
  CVT_PAIR(A[0], A[1], hi[0], lo[0]);
  CVT_PAIR(A[2], A[3], hi[1], lo[1]);
  CVT_PAIR(B[0], B[1], hi[2], lo[2]);
  CVT_PAIR(B[2], B[3], hi[3], lo[3]);
}

// ---------------- prep: split W into bf16 hi/lo in MFMA-B fragment order ----
// (proven R3/R5 version, unchanged)
__global__ __launch_bounds__(256) void prep_split(const float* __restrict__ tp,
                                                  const float* __restrict__ tw,
                                                  unsigned short* __restrict__ bsp,
                                                  float* __restrict__ bias,
                                                  float* __restrict__ coef) {
  const int n  = blockIdx.x;        // 0..63 (row of W-pad)
  const int j  = threadIdx.x;       // 0..255
  const int k0 = j * 8;
  f32x4 v0 = {0,0,0,0}, v1 = {0,0,0,0};
  if (n < NVALID) {
    const float* src = tp + (size_t)(n >> 2) * PPT + (n & 3) * D_IN + k0;
#pragma unroll
    for (int q = 0; q < 4; ++q) v0[q] = src[q];
#pragma unroll
    for (int q = 0; q < 4; ++q) v1[q] = src[4 + q];
  }
  u32x4 hi, lo;
  cvt8(v0, v1, hi, lo);
  const int ks = k0 >> 5, f = n >> 4;
  const int lane = (n & 15) | (((k0 >> 3) & 3) << 4);
  char* bb = (char*)bsp + ((size_t)(ks * 4 + f) * 2) * 1024 + (size_t)lane * 16;
  *(u32x4*)(bb)        = hi;
  *(u32x4*)(bb + 1024) = lo;

  if (blockIdx.x == 0) {
    int tid = threadIdx.x;
    if (tid < 64) {
      float b = 0.0f;
      if (tid < NVALID) { int t = tid >> 2, i = tid & 3; b = tp[t * PPT + 14336 + i]; }
      bias[tid] = b;
    } else if (tid < 64 + NT) {
      int t = tid - 64;
      const float* ll = tp + t * PPT + 14343;  // leaf_logits [8][2]
      float d0[8], d1[8];
#pragma unroll
      for (int le = 0; le < 8; ++le) {
        float aa = ll[2 * le], bb2 = ll[2 * le + 1];
        float m = fmaxf(aa, bb2);
        float e0 = __expf(aa - m), e1 = __expf(bb2 - m);
        float inv = 1.0f / (e0 + e1);
        d0[le] = e0 * inv; d1[le] = e1 * inv;
      }
      float ww = tw[t];
      float* c = coef + t * 10;
      c[0] = ww * (d0[0] + d0[2] + d0[4] + d0[6]);
      c[1] = ww * (d1[0] + d1[2] + d1[4] + d1[6]);
      c[2] = ww * (d0[1] - d0[2]);
      c[3] = ww * (d1[1] - d1[2]);
      c[4] = ww * (d0[3] - d0[4]);
      c[5] = ww * (d1[3] - d1[4]);
      c[6] = ww * (d0[5] - d0[6]);
      c[7] = ww * (d1[5] - d1[6]);
      c[8] = ww * d0[7];
      c[9] = ww * d1[7];
    }
  }
}

// ---------------- asm helpers -------------------------------------------------
__device__ __forceinline__ f32x4 gload4(const float* p) {
  f32x4 r;
  asm volatile("global_load_dwordx4 %0, %1, off" : "=v"(r) : "v"(p) : "memory");
  return r;
}
__device__ __forceinline__ u32x4 dsread16(uint32_t addr) {
  u32x4 r;
  asm volatile("ds_read_b128 %0, %1" : "=v"(r) : "v"(addr) : "memory");
  return r;
}
__device__ __forceinline__ void stage16(const void* g, void* l) {
  __builtin_amdgcn_global_load_lds(
      (const __attribute__((address_space(1))) void*)g,
      (__attribute__((address_space(3))) void*)l, 16, 0, 0);
}

// One K-step (BK=64), N-split wave (n half of cols). Per iter per wave:
//   top: vmcnt(WN) [drains s(t),A(t)]; barrier
//   8x ds_read of this wave's half-slab; cvt A(t)
//   lgkmcnt(0); issue stage(t+2) (2 ops) + A(t+2) (4 ops)
//   12 MFMA
#define ITERATION(tt, BUF, RC, WN, ISSUE)                                      \
  {                                                                            \
    WAITV(WN); SCHEDB;                                                         \
    __builtin_amdgcn_s_barrier();                                              \
    const uint32_t bb = sbase + (BUF) * 16384 + n4096 + l16;                   \
    u32x4 bfr[8];                                                              \
    _Pragma("unroll")                                                          \
    for (int q = 0; q < 4; ++q) bfr[q]     = dsread16(bb + q * 1024);          \
    _Pragma("unroll")                                                          \
    for (int q = 0; q < 4; ++q) bfr[4 + q] = dsread16(bb + 8192 + q * 1024);   \
    u32x4 ah0, al0, ah1, al1;                                                  \
    cvt8(RC[0], RC[1], ah0, al0);                                              \
    cvt8(RC[2], RC[3], ah1, al1);                                              \
    WAITL0; SCHEDB;                                                            \
    if (ISSUE) {                                                               \
      const int t2 = (tt) + 2;                                                 \
      const char* gsrc = bspb + (size_t)t2 * 16384 + w2048l16;                 \
      char* ldst = sBgen + (((BUF) + 2) % 3) * 16384 + w2048;                  \
      stage16(gsrc,        ldst);                                              \
      stage16(gsrc + 1024, ldst + 1024);                                       \
      const float* ap = xbase + t2 * 64;                                       \
      RC[0] = gload4(ap);      RC[1] = gload4(ap + 4);                         \
      RC[2] = gload4(ap + 32); RC[3] = gload4(ap + 36);                        \
    }                                                                          \
    _Pragma("unroll")                                                          \
    for (int ff = 0; ff < 2; ++ff) {                                           \
      bf16x8 bh = __builtin_bit_cast(bf16x8, bfr[2 * ff]);                     \
      bf16x8 bl = __builtin_bit_cast(bf16x8, bfr[2 * ff + 1]);                 \
      bf16x8 Ah = __builtin_bit_cast(bf16x8, ah0);                             \
      bf16x8 Al = __builtin_bit_cast(bf16x8, al0);                             \
      acc[ff] = __builtin_amdgcn_mfma_f32_16x16x32_bf16(Ah, bh, acc[ff],0,0,0);\
      acc[ff] = __builtin_amdgcn_mfma_f32_16x16x32_bf16(Al, bh, acc[ff],0,0,0);\
      acc[ff] = __builtin_amdgcn_mfma_f32_16x16x32_bf16(Ah, bl, acc[ff],0,0,0);\
    }                                                                          \
    _Pragma("unroll")                                                          \
    for (int ff = 0; ff < 2; ++ff) {                                           \
      bf16x8 bh = __builtin_bit_cast(bf16x8, bfr[4 + 2 * ff]);                 \
      bf16x8 bl = __builtin_bit_cast(bf16x8, bfr[4 + 2 * ff + 1]);             \
      bf16x8 Ah = __builtin_bit_cast(bf16x8, ah1);                             \
      bf16x8 Al = __builtin_bit_cast(bf16x8, al1);                             \
      acc[ff] = __builtin_amdgcn_mfma_f32_16x16x32_bf16(Ah, bh, acc[ff],0,0,0);\
      acc[ff] = __builtin_amdgcn_mfma_f32_16x16x32_bf16(Al, bh, acc[ff],0,0,0);\
      acc[ff] = __builtin_amdgcn_mfma_f32_16x16x32_bf16(Ah, bl, acc[ff],0,0,0);\
    }                                                                          \
  }

// Block = 512 threads (8 waves), BM=64. Wave w: m=w&3 (16-row group),
// n=w>>2 (column half). Grid 512 -> exactly 2 blocks/CU, 16 waves/CU (4/SIMD).
__global__ __launch_bounds__(512, 4) void tree_fused(
    const float* __restrict__ x,
    const unsigned short* __restrict__ bsp,
    const float* __restrict__ bias,
    const float* __restrict__ coef,
    float* __restrict__ out)
{
  __shared__ __align__(1024) unsigned char sB[3 * 16384];   // slab triple buffer

  const int tid = threadIdx.x;
  const int w   = tid >> 6;        // wave 0..7
  const int l   = tid & 63;
  const int rl  = l & 15;
  const int g   = l >> 4;
  const int m   = w & 3;
  const int n   = w >> 2;
  const int l16 = l * 16;
  const int n4096 = n * 4096;
  const int w2048 = w * 2048;
  const int w2048l16 = w2048 + l16;

  const int rowTile = blockIdx.x * 64 + m * 16;
  const float* xbase = x + (size_t)(rowTile + rl) * D_IN + g * 8;
  const char* bspb = (const char*)bsp;
  char* sBgen = (char*)&sB[0];
  const uint32_t sbase = (uint32_t)(uintptr_t)sBgen;

  f32x4 acc[2] = {};
  f32x4 rA[4], rB[4];

  // prologue: issue s0,A0,s1,A1 -> 12 outstanding vmem ops
  {
    stage16(bspb + w2048l16,        sBgen + w2048);
    stage16(bspb + w2048l16 + 1024, sBgen + w2048 + 1024);
    rA[0] = gload4(xbase);      rA[1] = gload4(xbase + 4);
    rA[2] = gload4(xbase + 32); rA[3] = gload4(xbase + 36);
    stage16(bspb + 16384 + w2048l16,        sBgen + 16384 + w2048);
    stage16(bspb + 16384 + w2048l16 + 1024, sBgen + 16384 + w2048 + 1024);
    rB[0] = gload4(xbase + 64); rB[1] = gload4(xbase + 68);
    rB[2] = gload4(xbase + 96); rB[3] = gload4(xbase + 100);
  }

  // main loop: period 6 (buf %3 x A-reg parity %2), 30 iters + 2 tail
  for (int tb = 0; tb < 30; tb += 6) {
    ITERATION(tb + 0, 0, rA, 6, 1);
    ITERATION(tb + 1, 1, rB, 6, 1);
    ITERATION(tb + 2, 2, rA, 6, 1);
    ITERATION(tb + 3, 0, rB, 6, 1);
    ITERATION(tb + 4, 1, rA, 6, 1);
    ITERATION(tb + 5, 2, rB, 6, 1);
  }
  ITERATION(30, 0, rA, 6, 0);     // outstanding 12 -> drain s30,A30
  ITERATION(31, 1, rB, 0, 0);     // drain s31,A31

  // ---- epilogue ----
  // strips aliased onto buf0 (last read iter 30; all waves passed barrier(31)
  // after their WAITL0(30) -> safe). partials onto buf2 (last read iter 29).
  float* sfl = (float*)sBgen;                     // [4][16][64] = 16 KB
  float* pp  = (float*)(sBgen + 2 * 16384);       // [4][2][16][2] = 1 KB

#pragma unroll
  for (int ff = 0; ff < 2; ++ff)
#pragma unroll
    for (int r = 0; r < 4; ++r)
      sfl[(m * 16 + 4 * g + r) * 64 + 32 * n + 16 * ff + rl] = acc[ff][r];
  __syncthreads();

  // wave (m,n): trees t = g + 4*(2n + jt2), jt2 in {0,1}; rows rl of group m
  float o0 = 0.0f, o1 = 0.0f;
#pragma unroll
  for (int jt2 = 0; jt2 < 2; ++jt2) {
    int t = g + 4 * (2 * n + jt2);
    if (t < NT) {
      const float* cf = coef + t * 10;
      float dd[4];
#pragma unroll
      for (int i = 0; i < 4; ++i) {
        float z = sfl[(m * 16 + rl) * 64 + 4 * t + i] + bias[4 * t + i];
        dd[i] = 1.0f / (1.0f + __expf(-z));
      }
      float s = 1.0f / (4.0f + dd[3] + 1e-8f);
      o0 += s * (cf[0] + dd[0] * cf[2] + dd[1] * cf[4] + dd[2] * cf[6] + dd[3] * cf[8]);
      o1 += s * (cf[1] + dd[0] * cf[3] + dd[1] * cf[5] + dd[2] * cf[7] + dd[3] * cf[9]);
    }
  }
  o0 += __shfl_xor(o0, 16); o0 += __shfl_xor(o0, 32);
  o1 += __shfl_xor(o1, 16); o1 += __shfl_xor(o1, 32);
  if (l < 16) {
    pp[((m * 2 + n) * 16 + rl) * 2 + 0] = o0;
    pp[((m * 2 + n) * 16 + rl) * 2 + 1] = o1;
  }
  __syncthreads();
  if (n == 0 && l < 16) {
    float a0 = pp[((m * 2) * 16 + rl) * 2 + 0] + pp[((m * 2 + 1) * 16 + rl) * 2 + 0];
    float a1 = pp[((m * 2) * 16 + rl) * 2 + 1] + pp[((m * 2 + 1) * 16 + rl) * 2 + 1];
    ((float2*)out)[rowTile + rl] = make_float2(a0, a1);
  }
}

// ---------------- launch ------------------------------------------------------
extern "C" void kernel_launch(void* const* d_in, const int* in_sizes, int n_in,
                              void* d_out, int out_size, void* d_ws, size_t ws_size,
                              hipStream_t stream) {
  (void)in_sizes; (void)n_in; (void)out_size; (void)ws_size;
  const float* x  = (const float*)d_in[0];
  const float* tp = (const float*)d_in[1];
  const float* tw = (const float*)d_in[2];
  float* out = (float*)d_out;

  unsigned short* bsp = (unsigned short*)d_ws;                    // 524288 B
  float* bias = (float*)((char*)d_ws + 524288);                   // 256 B
  float* coef = (float*)((char*)d_ws + 524288 + 256);             // 600 B

  prep_split<<<64, 256, 0, stream>>>(tp, tw, bsp, bias, coef);
  tree_fused<<<512, 512, 0, stream>>>(x, bsp, bias, coef, out);
}

// Round 8
// 67.753 us; speedup vs baseline: 1.1989x; 1.1989x over previous
//
#include <hip/hip_runtime.h>
#include <stdint.h>

#define D_IN    2048
#define NT      15
#define PPT     14359      // 7*(2048+1) + 8*2
#define NVALID  60         // 15 trees * 4 used internal nodes

typedef __bf16   bf16x8 __attribute__((ext_vector_type(8)));
typedef float    f32x4  __attribute__((ext_vector_type(4)));
typedef uint32_t u32x4  __attribute__((ext_vector_type(4)));

#define WAITV(n) asm volatile("s_waitcnt vmcnt(" #n ")" ::: "memory")
#define WAITL0   asm volatile("s_waitcnt lgkmcnt(0)" ::: "memory")
#define SCHEDB   __builtin_amdgcn_sched_barrier(0)

// pack two floats -> (hi bf16 pair, lo bf16 pair); lo = residual of truncation
#define CVT_PAIR(P, Q, HW, LW) do {                                   \
    uint32_t _up = __float_as_uint(P), _uq = __float_as_uint(Q);      \
    uint32_t _mp = _up & 0xFFFF0000u, _mq = _uq & 0xFFFF0000u;        \
    (HW) = (_up >> 16) | _mq;                                         \
    float _lp = (P) - __uint_as_float(_mp);                           \
    float _lq = (Q) - __uint_as_float(_mq);                           \
    (LW) = (__float_as_uint(_lp) >> 16) |                             \
           (__float_as_uint(_lq) & 0xFFFF0000u);                      \
  } while (0)

__device__ __forceinline__ void cvt8(const f32x4 A, const f32x4 B,
                                     u32x4& hi, u32x4& lo) {
  CVT_PAIR(A[0], A[1], hi[0], lo[0]);
  CVT_PAIR(A[2], A[3], hi[1], lo[1]);
  CVT_PAIR(B[0], B[1], hi[2], lo[2]);
  CVT_PAIR(B[2], B[3], hi[3], lo[3]);
}

// ---------------- prep: split W into bf16 hi/lo in MFMA-B fragment order ----
// (proven R3/R5 version, unchanged)
__global__ __launch_bounds__(256) void prep_split(const float* __restrict__ tp,
                                                  const float* __restrict__ tw,
                                                  unsigned short* __restrict__ bsp,
                                                  float* __restrict__ bias,
                                                  float* __restrict__ coef) {
  const int n  = blockIdx.x;        // 0..63 (row of W-pad)
  const int j  = threadIdx.x;       // 0..255
  const int k0 = j * 8;
  f32x4 v0 = {0,0,0,0}, v1 = {0,0,0,0};
  if (n < NVALID) {
    const float* src = tp + (size_t)(n >> 2) * PPT + (n & 3) * D_IN + k0;
#pragma unroll
    for (int q = 0; q < 4; ++q) v0[q] = src[q];
#pragma unroll
    for (int q = 0; q < 4; ++q) v1[q] = src[4 + q];
  }
  u32x4 hi, lo;
  cvt8(v0, v1, hi, lo);
  const int ks = k0 >> 5, f = n >> 4;
  const int lane = (n & 15) | (((k0 >> 3) & 3) << 4);
  char* bb = (char*)bsp + ((size_t)(ks * 4 + f) * 2) * 1024 + (size_t)lane * 16;
  *(u32x4*)(bb)        = hi;
  *(u32x4*)(bb + 1024) = lo;

  if (blockIdx.x == 0) {
    int tid = threadIdx.x;
    if (tid < 64) {
      float b = 0.0f;
      if (tid < NVALID) { int t = tid >> 2, i = tid & 3; b = tp[t * PPT + 14336 + i]; }
      bias[tid] = b;
    } else if (tid < 64 + NT) {
      int t = tid - 64;
      const float* ll = tp + t * PPT + 14343;  // leaf_logits [8][2]
      float d0[8], d1[8];
#pragma unroll
      for (int le = 0; le < 8; ++le) {
        float aa = ll[2 * le], bb2 = ll[2 * le + 1];
        float m = fmaxf(aa, bb2);
        float e0 = __expf(aa - m), e1 = __expf(bb2 - m);
        float inv = 1.0f / (e0 + e1);
        d0[le] = e0 * inv; d1[le] = e1 * inv;
      }
      float ww = tw[t];
      float* c = coef + t * 10;
      c[0] = ww * (d0[0] + d0[2] + d0[4] + d0[6]);
      c[1] = ww * (d1[0] + d1[2] + d1[4] + d1[6]);
      c[2] = ww * (d0[1] - d0[2]);
      c[3] = ww * (d1[1] - d1[2]);
      c[4] = ww * (d0[3] - d0[4]);
      c[5] = ww * (d1[3] - d1[4]);
      c[6] = ww * (d0[5] - d0[6]);
      c[7] = ww * (d1[5] - d1[6]);
      c[8] = ww * d0[7];
      c[9] = ww * d1[7];
    }
  }
}

// ---------------- asm helpers -------------------------------------------------
__device__ __forceinline__ f32x4 gload4f(const float* p) {
  f32x4 r;
  asm volatile("global_load_dwordx4 %0, %1, off" : "=v"(r) : "v"(p) : "memory");
  return r;
}
__device__ __forceinline__ u32x4 gload4u(const char* p) {
  u32x4 r;
  asm volatile("global_load_dwordx4 %0, %1, off" : "=v"(r) : "v"(p) : "memory");
  return r;
}
__device__ __forceinline__ u32x4 dsread16(uint32_t addr) {
  u32x4 r;
  asm volatile("ds_read_b128 %0, %1" : "=v"(r) : "v"(addr) : "memory");
  return r;
}
__device__ __forceinline__ void stage16(const void* g, void* l) {
  __builtin_amdgcn_global_load_lds(
      (const __attribute__((address_space(1))) void*)g,
      (__attribute__((address_space(3))) void*)l, 16, 0, 0);
}

// One K-step (BK=64). Barrier-free protocol, per-wave only:
//   A staged in wave-PRIVATE LDS (3 bufs, distance 2) via global_load_lds,
//   row-contiguous source, XOR-swizzled slots (slot ^= rl&7).
//   B read straight from bsp (L1/L2-hot) into regs, half-iter ahead.
//   steady waits: W3=vmcnt(12) [drains A(t+1),B(t)h0], W6=vmcnt(12) [B(t)h1].
#define ITERATION(tt, AB, BC0, BC1, BN0, BN1, W3, W6, ISSA, ISSB)              \
  {                                                                            \
    if (ISSA) {                                                                \
      const int t2 = (tt) + 2;                                                 \
      char* ldst = sAw + (((AB) + 2) % 3) * 4096;                              \
      stage16(xsb0 + t2 * 64, ldst);                                           \
      stage16(xsb1 + t2 * 64, ldst + 1024);                                    \
      stage16(xsb2 + t2 * 64, ldst + 2048);                                    \
      stage16(xsb3 + t2 * 64, ldst + 3072);                                    \
    }                                                                          \
    WAITV(W3); SCHEDB;                                                         \
    const uint32_t ab_ = sabase + (AB) * 4096;                                 \
    u32x4 ar0 = dsread16(ab_ + sw0a);                                          \
    u32x4 ar1 = dsread16(ab_ + sw0b);                                          \
    u32x4 ar2 = dsread16(ab_ + sw1a);                                          \
    u32x4 ar3 = dsread16(ab_ + sw1b);                                          \
    WAITL0; SCHEDB;                                                            \
    u32x4 ah0, al0;                                                            \
    cvt8(__builtin_bit_cast(f32x4, ar0), __builtin_bit_cast(f32x4, ar1),       \
         ah0, al0);                                                            \
    _Pragma("unroll")                                                          \
    for (int f = 0; f < 4; ++f) {                                              \
      bf16x8 bh = __builtin_bit_cast(bf16x8, BC0[2 * f]);                      \
      bf16x8 bl = __builtin_bit_cast(bf16x8, BC0[2 * f + 1]);                  \
      bf16x8 Ah = __builtin_bit_cast(bf16x8, ah0);                             \
      bf16x8 Al = __builtin_bit_cast(bf16x8, al0);                             \
      acc[f] = __builtin_amdgcn_mfma_f32_16x16x32_bf16(Ah, bh, acc[f], 0,0,0); \
      acc[f] = __builtin_amdgcn_mfma_f32_16x16x32_bf16(Al, bh, acc[f], 0,0,0); \
      acc[f] = __builtin_amdgcn_mfma_f32_16x16x32_bf16(Ah, bl, acc[f], 0,0,0); \
    }                                                                          \
    if (ISSB) {                                                                \
      const char* bsrc = bspb + (size_t)((tt) + 1) * 16384 + l16;              \
      _Pragma("unroll")                                                        \
      for (int q = 0; q < 8; ++q) BN0[q] = gload4u(bsrc + q * 1024);           \
    }                                                                          \
    WAITV(W6); SCHEDB;                                                         \
    u32x4 ah1, al1;                                                            \
    cvt8(__builtin_bit_cast(f32x4, ar2), __builtin_bit_cast(f32x4, ar3),       \
         ah1, al1);                                                            \
    _Pragma("unroll")                                                          \
    for (int f = 0; f < 4; ++f) {                                              \
      bf16x8 bh = __builtin_bit_cast(bf16x8, BC1[2 * f]);                      \
      bf16x8 bl = __builtin_bit_cast(bf16x8, BC1[2 * f + 1]);                  \
      bf16x8 Ah = __builtin_bit_cast(bf16x8, ah1);                             \
      bf16x8 Al = __builtin_bit_cast(bf16x8, al1);                             \
      acc[f] = __builtin_amdgcn_mfma_f32_16x16x32_bf16(Ah, bh, acc[f], 0,0,0); \
      acc[f] = __builtin_amdgcn_mfma_f32_16x16x32_bf16(Al, bh, acc[f], 0,0,0); \
      acc[f] = __builtin_amdgcn_mfma_f32_16x16x32_bf16(Ah, bl, acc[f], 0,0,0); \
    }                                                                          \
    if (ISSB) {                                                                \
      const char* bsrc = bspb + (size_t)((tt) + 1) * 16384 + l16;              \
      _Pragma("unroll")                                                        \
      for (int q = 0; q < 8; ++q) BN1[q] = gload4u(bsrc + (8 + q) * 1024);     \
    }                                                                          \
  }

__global__ __launch_bounds__(256) void tree_fused(
    const float* __restrict__ x,
    const unsigned short* __restrict__ bsp,
    const float* __restrict__ bias,
    const float* __restrict__ coef,
    float* __restrict__ out)
{
  __shared__ __align__(1024) unsigned char sA[4 * 3 * 4096];  // per-wave A bufs
  __shared__ float strips[4][16][65];                         // per-wave epilogue

  const int tid = threadIdx.x;
  const int w   = tid >> 6;        // wave 0..3
  const int l   = tid & 63;
  const int rl  = l & 15;
  const int g   = l >> 4;
  const int l16 = l * 16;
  const int r7  = rl & 7;

  const int rowTile = blockIdx.x * 64 + w * 16;
  const char* bspb = (const char*)bsp;
  char* sAw = (char*)&sA[0] + w * 12288;
  const uint32_t sabase = (uint32_t)(uintptr_t)sAw;

  // swizzled ds_read offsets for this lane: slot X=2g+c2 (h0), 8+2g+c2 (h1)
  const uint32_t sw0a = (uint32_t)rl * 256 + (uint32_t)(((2 * g + 0) ^ r7) << 4);
  const uint32_t sw0b = (uint32_t)rl * 256 + (uint32_t)(((2 * g + 1) ^ r7) << 4);
  const uint32_t sw1a = (uint32_t)rl * 256 + (uint32_t)(((8 + 2 * g + 0) ^ r7) << 4);
  const uint32_t sw1b = (uint32_t)rl * 256 + (uint32_t)(((8 + 2 * g + 1) ^ r7) << 4);

  // staging source bases: call c covers rows rowTile+4c+(l>>4), 256B contiguous
  // (16B chunks permuted by s^row7 so linear LDS dest == swizzled layout)
  const int sr0 = 0 * 4 + (l >> 4), sr1 = 1 * 4 + (l >> 4);
  const int sr2 = 2 * 4 + (l >> 4), sr3 = 3 * 4 + (l >> 4);
  const float* xsb0 = x + (size_t)(rowTile + sr0) * D_IN + (((l & 15) ^ (sr0 & 7)) << 2);
  const float* xsb1 = x + (size_t)(rowTile + sr1) * D_IN + (((l & 15) ^ (sr1 & 7)) << 2);
  const float* xsb2 = x + (size_t)(rowTile + sr2) * D_IN + (((l & 15) ^ (sr2 & 7)) << 2);
  const float* xsb3 = x + (size_t)(rowTile + sr3) * D_IN + (((l & 15) ^ (sr3 & 7)) << 2);

  f32x4 acc[4] = {};
  u32x4 be0[8], be1[8], bo0[8], bo1[8];    // B regs: even/odd iter, halves 0/1

  // ---- prologue: issue A(0),A(1) to LDS; B(0)h0,h1 to regs (24 vmem) ----
  {
    stage16(xsb0, sAw);            stage16(xsb1, sAw + 1024);
    stage16(xsb2, sAw + 2048);     stage16(xsb3, sAw + 3072);
    stage16(xsb0 + 64, sAw + 4096);        stage16(xsb1 + 64, sAw + 4096 + 1024);
    stage16(xsb2 + 64, sAw + 4096 + 2048); stage16(xsb3 + 64, sAw + 4096 + 3072);
    const char* bsrc = bspb + l16;
#pragma unroll
    for (int q = 0; q < 8; ++q) be0[q] = gload4u(bsrc + q * 1024);
#pragma unroll
    for (int q = 0; q < 8; ++q) be1[q] = gload4u(bsrc + (8 + q) * 1024);
  }
  __syncthreads();   // only barrier: orders nothing in-loop (waves free-run)

  // ---- main loop: period 6 (A-buf %3 x B-reg parity %2), iters 0..29 ----
  for (int tb = 0; tb < 30; tb += 6) {
    ITERATION(tb + 0, 0, be0, be1, bo0, bo1, 12, 12, 1, 1);
    ITERATION(tb + 1, 1, bo0, bo1, be0, be1, 12, 12, 1, 1);
    ITERATION(tb + 2, 2, be0, be1, bo0, bo1, 12, 12, 1, 1);
    ITERATION(tb + 3, 0, bo0, bo1, be0, be1, 12, 12, 1, 1);
    ITERATION(tb + 4, 1, be0, be1, bo0, bo1, 12, 12, 1, 1);
    ITERATION(tb + 5, 2, bo0, bo1, be0, be1, 12, 12, 1, 1);
  }
  // tails: t=30 (no A-issue), t=31 (no issues, drain)
  ITERATION(30, 0, be0, be1, bo0, bo1, 8, 8, 0, 1);
  ITERATION(31, 1, bo0, bo1, be0, be1, 8, 0, 0, 0);

  // ---- epilogue: per-wave strip transpose + folded tree math (no barrier) ----
#pragma unroll
  for (int f = 0; f < 4; ++f)
#pragma unroll
    for (int r = 0; r < 4; ++r)
      strips[w][4 * g + r][16 * f + rl] = acc[f][r];
  WAITL0;

  float o0 = 0.0f, o1 = 0.0f;
#pragma unroll
  for (int jt = 0; jt < 4; ++jt) {
    int t = g + 4 * jt;
    if (t < NT) {
      const float* cf = coef + t * 10;
      float dd[4];
#pragma unroll
      for (int i = 0; i < 4; ++i) {
        float z = strips[w][rl][4 * t + i] + bias[4 * t + i];
        dd[i] = 1.0f / (1.0f + __expf(-z));
      }
      float s = 1.0f / (4.0f + dd[3] + 1e-8f);
      o0 += s * (cf[0] + dd[0] * cf[2] + dd[1] * cf[4] + dd[2] * cf[6] + dd[3] * cf[8]);
      o1 += s * (cf[1] + dd[0] * cf[3] + dd[1] * cf[5] + dd[2] * cf[7] + dd[3] * cf[9]);
    }
  }
  o0 += __shfl_xor(o0, 16); o0 += __shfl_xor(o0, 32);
  o1 += __shfl_xor(o1, 16); o1 += __shfl_xor(o1, 32);
  if (l < 16) {
    ((float2*)out)[rowTile + rl] = make_float2(o0, o1);
  }
}

// ---------------- launch ------------------------------------------------------
extern "C" void kernel_launch(void* const* d_in, const int* in_sizes, int n_in,
                              void* d_out, int out_size, void* d_ws, size_t ws_size,
                              hipStream_t stream) {
  (void)in_sizes; (void)n_in; (void)out_size; (void)ws_size;
  const float* x  = (const float*)d_in[0];
  const float* tp = (const float*)d_in[1];
  const float* tw = (const float*)d_in[2];
  float* out = (float*)d_out;

  unsigned short* bsp = (unsigned short*)d_ws;                    // 524288 B
  float* bias = (float*)((char*)d_ws + 524288);                   // 256 B
  float* coef = (float*)((char*)d_ws + 524288 + 256);             // 600 B

  prep_split<<<64, 256, 0, stream>>>(tp, tw, bsp, bias, coef);
  tree_fused<<<512, 256, 0, stream>>>(x, bsp, bias, coef, out);
}